// Round 5
// baseline (542.974 us; speedup 1.0000x reference)
//
#include <hip/hip_runtime.h>

typedef unsigned short u16;
using bf16x8 = __attribute__((ext_vector_type(8))) __bf16;
using f32x4  = __attribute__((ext_vector_type(4))) float;
using s16x8  = __attribute__((ext_vector_type(8))) short;
using s16x4  = __attribute__((ext_vector_type(4))) short;

#define AS1 __attribute__((address_space(1)))
#define AS3 __attribute__((address_space(3)))

__device__ __forceinline__ void gload16(const u16* g, u16* l) {
  __builtin_amdgcn_global_load_lds((AS1 void*)(size_t)g, (AS3 void*)l, 16, 0, 0);
}

__device__ __forceinline__ u16 f2bf(float f) {
  unsigned u = __float_as_uint(f);
  u += 0x7fffu + ((u >> 16) & 1u);   // round-to-nearest-even
  return (u16)(u >> 16);
}
__device__ __forceinline__ float bf2f(u16 h) {
  return __uint_as_float(((unsigned)h) << 16);
}

// ---------------- elementwise f32 -> bf16 ----------------
__global__ __launch_bounds__(256) void cast_bf16_kernel(const float* __restrict__ x,
                                                        u16* __restrict__ y, int n) {
  int i = (blockIdx.x * 256 + threadIdx.x) * 4;
  if (i + 3 < n) {
    float4 v = *reinterpret_cast<const float4*>(x + i);
    s16x4 o;
    o[0] = (short)f2bf(v.x); o[1] = (short)f2bf(v.y);
    o[2] = (short)f2bf(v.z); o[3] = (short)f2bf(v.w);
    *reinterpret_cast<s16x4*>(y + i) = o;
  }
}

// ---------------- W [K][N] f32 -> WT [N][K] bf16 (64x64 tiles) ----------------
__global__ __launch_bounds__(256) void transpose_cast_kernel(const float* __restrict__ W,
                                                             u16* __restrict__ WT,
                                                             int K, int N) {
  __shared__ u16 tile[64][72];
  const int t = threadIdx.x;
  const int nb = blockIdx.x * 64, kb = blockIdx.y * 64;
  const int rr = t >> 3;        // 0..31
  const int cc = (t & 7) * 8;   // 0..56
#pragma unroll
  for (int pass = 0; pass < 2; ++pass) {
    const float* src = W + (size_t)(kb + pass * 32 + rr) * N + nb + cc;
    float4 a = *reinterpret_cast<const float4*>(src);
    float4 b = *reinterpret_cast<const float4*>(src + 4);
    u16* tr = &tile[pass * 32 + rr][cc];
    tr[0] = f2bf(a.x); tr[1] = f2bf(a.y); tr[2] = f2bf(a.z); tr[3] = f2bf(a.w);
    tr[4] = f2bf(b.x); tr[5] = f2bf(b.y); tr[6] = f2bf(b.z); tr[7] = f2bf(b.w);
  }
  __syncthreads();
#pragma unroll
  for (int pass = 0; pass < 2; ++pass) {
    s16x8 v;
#pragma unroll
    for (int j = 0; j < 8; ++j) v[j] = (short)tile[cc + j][pass * 32 + rr];
    *reinterpret_cast<s16x8*>(WT + (size_t)(nb + pass * 32 + rr) * K + kb + cc) = v;
  }
}

// ---------------- RMSNorm (bf16 in/out, f32 weight) ----------------
__global__ __launch_bounds__(256) void rmsnorm_kernel(const u16* __restrict__ x,
                                                      const float* __restrict__ w,
                                                      u16* __restrict__ y,
                                                      int R, int xs, int ys) {
  const int row = blockIdx.x, t = threadIdx.x;
  const u16* xr = x + (size_t)row * xs;
  float ss = 0.f;
  for (int i = t; i < R; i += 256) { float f = bf2f(xr[i]); ss += f * f; }
#pragma unroll
  for (int m = 32; m >= 1; m >>= 1) ss += __shfl_xor(ss, m);
  __shared__ float red[4];
  if ((t & 63) == 0) red[t >> 6] = ss;
  __syncthreads();
  float tot = red[0] + red[1] + red[2] + red[3];
  float r = rsqrtf(tot / (float)R + 1e-6f);
  u16* yr = y + (size_t)row * ys;
  for (int i = t; i < R; i += 256) yr[i] = f2bf(bf2f(xr[i]) * r * w[i]);
}

// ---------------- RoPE cos/sin table: [2048][32] each ----------------
__global__ __launch_bounds__(256) void rope_table_kernel(float* __restrict__ cost,
                                                         float* __restrict__ sint) {
  int idx = blockIdx.x * 256 + threadIdx.x;   // 65536
  int pos = idx >> 5, j = idx & 31;
  float inv = __expf(-(float)j * (9.210340371976184f / 32.0f));  // 10000^(-j/32)
  float f = (float)pos * inv;
  cost[idx] = cosf(f);
  sint[idx] = sinf(f);
}

// ---------------- qf build (vectorized): q [s][h*192] -> qf [h][s][192], RoPE + scale ----------------
__global__ __launch_bounds__(256) void build_qf_kernel(const u16* __restrict__ q,
                                                       const float* __restrict__ cost,
                                                       const float* __restrict__ sint,
                                                       u16* __restrict__ qf) {
  int tid = blockIdx.x * 256 + threadIdx.x;
  int o8 = tid * 8;
  if (o8 >= 32 * 2048 * 192) return;
  const float scale = 0.07216878364870323f;  // 192^-0.5 (folded into q)
  int c = (o8 % 192) >> 3;  // chunk 0..23
  int rest = o8 / 192;
  int s = rest & 2047, h = rest >> 11;
  const u16* qrow = q + ((size_t)s * 32 + h) * 192;
  s16x8 out;
  if (c < 16) {
    s16x8 v = *reinterpret_cast<const s16x8*>(qrow + c * 8);
#pragma unroll
    for (int j = 0; j < 8; ++j) out[j] = (short)f2bf(bf2f((u16)v[j]) * scale);
  } else {
    int j0 = c * 8 - 128;
    bool lo = j0 < 32;
    int jj0 = lo ? j0 : j0 - 32;
    s16x8 a = *reinterpret_cast<const s16x8*>(qrow + 128 + 2 * jj0);
    s16x8 b = *reinterpret_cast<const s16x8*>(qrow + 128 + 2 * jj0 + 8);
    float4 c0 = *reinterpret_cast<const float4*>(cost + s * 32 + jj0);
    float4 c1 = *reinterpret_cast<const float4*>(cost + s * 32 + jj0 + 4);
    float4 s0 = *reinterpret_cast<const float4*>(sint + s * 32 + jj0);
    float4 s1 = *reinterpret_cast<const float4*>(sint + s * 32 + jj0 + 4);
    float cs[8] = {c0.x, c0.y, c0.z, c0.w, c1.x, c1.y, c1.z, c1.w};
    float sn[8] = {s0.x, s0.y, s0.z, s0.w, s1.x, s1.y, s1.z, s1.w};
#pragma unroll
    for (int j = 0; j < 8; ++j) {
      float x0 = bf2f((u16)((j < 4) ? a[2 * j] : b[2 * j - 8]));
      float x1 = bf2f((u16)((j < 4) ? a[2 * j + 1] : b[2 * j - 7]));
      float v = lo ? (x0 * cs[j] - x1 * sn[j]) : (x1 * cs[j] + x0 * sn[j]);
      out[j] = (short)f2bf(v * scale);
    }
  }
  *reinterpret_cast<s16x8*>(qf + o8) = out;
}

// ---------------- kf build (vectorized): kv [s][h*256], ckv(stride 2112) -> kf [h][s][192] ----------------
__global__ __launch_bounds__(256) void build_kf_kernel(const u16* __restrict__ kv,
                                                       const u16* __restrict__ ckv,
                                                       const float* __restrict__ cost,
                                                       const float* __restrict__ sint,
                                                       u16* __restrict__ kf) {
  int tid = blockIdx.x * 256 + threadIdx.x;
  int o8 = tid * 8;
  if (o8 >= 32 * 2048 * 192) return;
  int c = (o8 % 192) >> 3;
  int rest = o8 / 192;
  int s = rest & 2047, h = rest >> 11;
  s16x8 out;
  if (c < 16) {
    out = *reinterpret_cast<const s16x8*>(kv + ((size_t)s * 32 + h) * 256 + c * 8);
  } else {
    int j0 = c * 8 - 128;
    bool lo = j0 < 32;
    int jj0 = lo ? j0 : j0 - 32;
    const u16* crow = ckv + (size_t)s * 2112 + 512;
    s16x8 a = *reinterpret_cast<const s16x8*>(crow + 2 * jj0);
    s16x8 b = *reinterpret_cast<const s16x8*>(crow + 2 * jj0 + 8);
    float4 c0 = *reinterpret_cast<const float4*>(cost + s * 32 + jj0);
    float4 c1 = *reinterpret_cast<const float4*>(cost + s * 32 + jj0 + 4);
    float4 s0 = *reinterpret_cast<const float4*>(sint + s * 32 + jj0);
    float4 s1 = *reinterpret_cast<const float4*>(sint + s * 32 + jj0 + 4);
    float cs[8] = {c0.x, c0.y, c0.z, c0.w, c1.x, c1.y, c1.z, c1.w};
    float sn[8] = {s0.x, s0.y, s0.z, s0.w, s1.x, s1.y, s1.z, s1.w};
#pragma unroll
    for (int j = 0; j < 8; ++j) {
      float x0 = bf2f((u16)((j < 4) ? a[2 * j] : b[2 * j - 8]));
      float x1 = bf2f((u16)((j < 4) ? a[2 * j + 1] : b[2 * j - 7]));
      float v = lo ? (x0 * cs[j] - x1 * sn[j]) : (x1 * cs[j] + x0 * sn[j]);
      out[j] = (short)f2bf(v);
    }
  }
  *reinterpret_cast<s16x8*>(kf + o8) = out;
}

// ---------------- vT build: kv [s][h*256+128+d] -> vT [h][128][2048] ----------------
__global__ __launch_bounds__(256) void vt_build_kernel(const u16* __restrict__ kv,
                                                       u16* __restrict__ vT) {
  __shared__ u16 tile[64][72];
  const int t = threadIdx.x;
  const int sb = blockIdx.x * 64, db = blockIdx.y * 64, h = blockIdx.z;
  const int rr = t >> 3, cc = (t & 7) * 8;
#pragma unroll
  for (int pass = 0; pass < 2; ++pass) {
    const u16* src = kv + (size_t)(sb + pass * 32 + rr) * 8192 + h * 256 + 128 + db + cc;
    s16x8 v = *reinterpret_cast<const s16x8*>(src);
#pragma unroll
    for (int j = 0; j < 8; ++j) tile[pass * 32 + rr][cc + j] = (u16)v[j];
  }
  __syncthreads();
#pragma unroll
  for (int pass = 0; pass < 2; ++pass) {
    s16x8 v;
#pragma unroll
    for (int j = 0; j < 8; ++j) v[j] = (short)tile[cc + j][pass * 32 + rr];
    *reinterpret_cast<s16x8*>(vT + ((size_t)h * 128 + db + pass * 32 + rr) * 2048 + sb + cc) = v;
  }
}

// ---------------- GEMM: C[M][N] = A[M][K](bf16) * BT[N][K](bf16)^T ----------------
// 128x128 tile, BK=32, 4 waves (2x2), global_load_lds staging (m97 pattern).
template <int OUT_BF16>
__global__ __launch_bounds__(256) void gemm_bt_kernel(const u16* __restrict__ A,
                                                      const u16* __restrict__ BT,
                                                      void* __restrict__ Cv,
                                                      int M, int N, int K) {
  __shared__ __align__(16) u16 As[128 * 32];
  __shared__ __align__(16) u16 Bs[128 * 32];
  const int t = threadIdx.x;
  const int lane = t & 63, wave = t >> 6;
  const int wr = wave >> 1, wc = wave & 1;
  const int row0 = blockIdx.y * 128, col0 = blockIdx.x * 128;
  const int srow = t >> 2;          // 0..63
  const int sk = (t & 3) * 8;       // k offset within BK
  const int lrow = lane & 15, lkg = lane >> 4;
  const int aoff = (wr * 64 + lrow) * 32 + lkg * 8;
  const int boff = (wc * 64 + lrow) * 32 + lkg * 8;

  int br0 = col0 + srow;      if (br0 > N - 1) br0 = N - 1;
  int br1 = col0 + 64 + srow; if (br1 > N - 1) br1 = N - 1;
  const int ar0 = row0 + srow, ar1 = row0 + 64 + srow;

  f32x4 acc[4][4];
#pragma unroll
  for (int m = 0; m < 4; ++m)
#pragma unroll
    for (int n = 0; n < 4; ++n) acc[m][n] = 0.f;

  for (int k0 = 0; k0 < K; k0 += 32) {
    gload16(A  + (size_t)ar0 * K + k0 + sk, &As[srow * 32 + sk]);
    gload16(A  + (size_t)ar1 * K + k0 + sk, &As[(64 + srow) * 32 + sk]);
    gload16(BT + (size_t)br0 * K + k0 + sk, &Bs[srow * 32 + sk]);
    gload16(BT + (size_t)br1 * K + k0 + sk, &Bs[(64 + srow) * 32 + sk]);
    __syncthreads();
    bf16x8 af[4], bb[4];
#pragma unroll
    for (int m = 0; m < 4; ++m)
      af[m] = *reinterpret_cast<const bf16x8*>(&As[aoff + m * 512]);
#pragma unroll
    for (int n = 0; n < 4; ++n)
      bb[n] = *reinterpret_cast<const bf16x8*>(&Bs[boff + n * 512]);
#pragma unroll
    for (int m = 0; m < 4; ++m)
#pragma unroll
      for (int n = 0; n < 4; ++n)
        acc[m][n] = __builtin_amdgcn_mfma_f32_16x16x32_bf16(af[m], bb[n], acc[m][n], 0, 0, 0);
    __syncthreads();
  }

#pragma unroll
  for (int m = 0; m < 4; ++m) {
#pragma unroll
    for (int n = 0; n < 4; ++n) {
      int col = col0 + wc * 64 + n * 16 + lrow;
      if (col < N) {
#pragma unroll
        for (int i = 0; i < 4; ++i) {
          int row = row0 + wr * 64 + m * 16 + lkg * 4 + i;
          size_t idx = (size_t)row * N + col;
          if (OUT_BF16) ((u16*)Cv)[idx] = f2bf(acc[m][n][i]);
          else          ((float*)Cv)[idx] = acc[m][n][i];
        }
      }
    }
  }
}

// ---------------- causal flash attention (128-row blocks, 32 rows/wave, dbuf K/V) ----------------
// grid (h=32, pair=8): 256 blocks = 1/CU; consecutive bids = same pair, all heads ->
// head h pinned to XCD h%8 (L2 locality). Block handles qb=pair and qb=15-pair
// (128 rows each; constant 34 KV-64 iters). 256 thr = 4 waves; wave w owns rows
// qb*128+w*32..+32 (two 16-row halves -> each K/V LDS fragment feeds 2 MFMAs).
// K/V double-buffered via global_load_lds in fragment order; counted vmcnt(10)
// keeps next-tile prefetch in flight across raw s_barriers (T3/T4).
__global__ __launch_bounds__(256, 1) void mla_attn_kernel(const u16* __restrict__ qf,
                                                          const u16* __restrict__ kf,
                                                          const u16* __restrict__ vT,
                                                          u16* __restrict__ o) {
  const int h = blockIdx.x, pairi = blockIdx.y;
  const int t = threadIdx.x, wave = t >> 6, lane = t & 63;
  const int lrow = lane & 15, lkg = lane >> 4;
  __shared__ __align__(16) u16 Kt[2][24 * 512];   // (cg,kk): K[cg*16+l&15][kk*32+(l>>4)*8]
  __shared__ __align__(16) u16 Vt[2][16 * 512];   // (f,ck):  vT[f*16+l&15][ck*32+(l>>4)*8]
  __shared__ __align__(16) u16 Pl[4][32][72];

  // staging sources: wave stages K rows cg=wave, V d-rows f=2w,2w+1
  const u16* ksrc0 = kf + ((size_t)h * 2048 + wave * 16 + lrow) * 192 + lkg * 8;
  const u16* vsrc0 = vT + ((size_t)h * 128 + wave * 32 + lrow) * 2048 + lkg * 8;

  for (int qq = 0; qq < 2; ++qq) {
    const int qb = qq ? (15 - pairi) : pairi;
    const int qbase = qb * 128 + wave * 32;   // wave's first q row

    // Q fragments: 2 row-halves x 6 k-chunks
    bf16x8 qfr[2][6];
#pragma unroll
    for (int r = 0; r < 2; ++r) {
      const u16* qp = qf + ((size_t)h * 2048 + qbase + r * 16 + lrow) * 192 + lkg * 8;
#pragma unroll
      for (int kk = 0; kk < 6; ++kk)
        qfr[r][kk] = *reinterpret_cast<const bf16x8*>(qp + kk * 32);
    }

    f32x4 acc[2][8];
#pragma unroll
    for (int r = 0; r < 2; ++r)
#pragma unroll
      for (int f = 0; f < 8; ++f) acc[r][f] = 0.f;
    float m_run[2][4], l_run[2][4];
#pragma unroll
    for (int r = 0; r < 2; ++r)
#pragma unroll
      for (int i = 0; i < 4; ++i) { m_run[r][i] = -__builtin_inff(); l_run[r][i] = 0.f; }

    const int nt = (qb + 1) * 2;   // KV tiles of 64

    // prologue: stage tile 0 into buffer 0
    {
      const u16* ks = ksrc0;
#pragma unroll
      for (int kk = 0; kk < 6; ++kk) gload16(ks + kk * 32, &Kt[0][(wave * 6 + kk) * 512]);
#pragma unroll
      for (int j = 0; j < 4; ++j)
        gload16(vsrc0 + (size_t)(j >> 1) * 16 * 2048 + (j & 1) * 32, &Vt[0][(wave * 4 + j) * 512]);
    }

    for (int it = 0; it < nt; ++it) {
      const int kt = it * 64;
      if (it + 1 < nt) {   // prefetch next tile into other buffer
        const int nb = (it + 1) & 1, nkt = kt + 64;
        const u16* ks = ksrc0 + (size_t)nkt * 192;
#pragma unroll
        for (int kk = 0; kk < 6; ++kk) gload16(ks + kk * 32, &Kt[nb][(wave * 6 + kk) * 512]);
#pragma unroll
        for (int j = 0; j < 4; ++j)
          gload16(vsrc0 + (size_t)(j >> 1) * 16 * 2048 + nkt + (j & 1) * 32,
                  &Vt[nb][(wave * 4 + j) * 512]);
        asm volatile("s_waitcnt vmcnt(10)" ::: "memory");  // current tile drained, prefetch in flight
      } else {
        asm volatile("s_waitcnt vmcnt(0)" ::: "memory");
      }
      __builtin_amdgcn_s_barrier();
      __builtin_amdgcn_sched_barrier(0);

      const u16* Kb = &Kt[it & 1][0];
      const u16* Vb = &Vt[it & 1][0];
      if (kt <= qbase + 31) {   // wave-uniform: skip fully-masked diagonal tiles
        // ---- S = Q K^T: 48 MFMA on 24 K-fragment reads (2x reuse) ----
        f32x4 sv[2][4];
#pragma unroll
        for (int r = 0; r < 2; ++r)
#pragma unroll
          for (int cg = 0; cg < 4; ++cg) sv[r][cg] = 0.f;
#pragma unroll
        for (int cg = 0; cg < 4; ++cg)
#pragma unroll
          for (int kk = 0; kk < 6; ++kk) {
            bf16x8 kfr = *reinterpret_cast<const bf16x8*>(&Kb[(cg * 6 + kk) * 512 + lane * 8]);
            sv[0][cg] = __builtin_amdgcn_mfma_f32_16x16x32_bf16(qfr[0][kk], kfr, sv[0][cg], 0, 0, 0);
            sv[1][cg] = __builtin_amdgcn_mfma_f32_16x16x32_bf16(qfr[1][kk], kfr, sv[1][cg], 0, 0, 0);
          }
        // ---- causal mask (diagonal region only) ----
        if (kt + 64 > qbase) {
#pragma unroll
          for (int r = 0; r < 2; ++r)
#pragma unroll
            for (int cg = 0; cg < 4; ++cg) {
              int kvcol = kt + cg * 16 + lrow;
              int rowb = qbase + r * 16 + lkg * 4;
#pragma unroll
              for (int i = 0; i < 4; ++i)
                if (kvcol > rowb + i) sv[r][cg][i] = -__builtin_inff();
            }
        }
        // ---- online softmax per row-half ----
#pragma unroll
        for (int r = 0; r < 2; ++r) {
          float tmax[4], mnew[4], alpha[4], rsum[4];
#pragma unroll
          for (int i = 0; i < 4; ++i)
            tmax[i] = fmaxf(fmaxf(sv[r][0][i], sv[r][1][i]), fmaxf(sv[r][2][i], sv[r][3][i]));
#pragma unroll
          for (int m = 8; m >= 1; m >>= 1)
#pragma unroll
            for (int i = 0; i < 4; ++i) tmax[i] = fmaxf(tmax[i], __shfl_xor(tmax[i], m));
#pragma unroll
          for (int i = 0; i < 4; ++i) {
            mnew[i] = fmaxf(m_run[r][i], tmax[i]);
#pragma unroll
            for (int cg = 0; cg < 4; ++cg) sv[r][cg][i] = __expf(sv[r][cg][i] - mnew[i]);
            rsum[i] = (sv[r][0][i] + sv[r][1][i]) + (sv[r][2][i] + sv[r][3][i]);
          }
#pragma unroll
          for (int m = 8; m >= 1; m >>= 1)
#pragma unroll
            for (int i = 0; i < 4; ++i) rsum[i] += __shfl_xor(rsum[i], m);
#pragma unroll
          for (int i = 0; i < 4; ++i) {
            alpha[i] = __expf(m_run[r][i] - mnew[i]);
            l_run[r][i] = l_run[r][i] * alpha[i] + rsum[i];
            m_run[r][i] = mnew[i];
          }
#pragma unroll
          for (int f = 0; f < 8; ++f)
#pragma unroll
            for (int i = 0; i < 4; ++i) acc[r][f][i] *= alpha[i];
          // P -> bf16 -> per-wave LDS
#pragma unroll
          for (int cg = 0; cg < 4; ++cg)
#pragma unroll
            for (int i = 0; i < 4; ++i)
              Pl[wave][r * 16 + lkg * 4 + i][cg * 16 + lrow] = f2bf(sv[r][cg][i]);
        }
        // ---- O += P V: 32 MFMA on 16 V-fragment reads (2x reuse) ----
#pragma unroll
        for (int ck = 0; ck < 2; ++ck) {
          bf16x8 pf0 = *reinterpret_cast<const bf16x8*>(&Pl[wave][lrow][ck * 32 + lkg * 8]);
          bf16x8 pf1 = *reinterpret_cast<const bf16x8*>(&Pl[wave][16 + lrow][ck * 32 + lkg * 8]);
#pragma unroll
          for (int f = 0; f < 8; ++f) {
            bf16x8 vfr = *reinterpret_cast<const bf16x8*>(&Vb[(f * 2 + ck) * 512 + lane * 8]);
            acc[0][f] = __builtin_amdgcn_mfma_f32_16x16x32_bf16(pf0, vfr, acc[0][f], 0, 0, 0);
            acc[1][f] = __builtin_amdgcn_mfma_f32_16x16x32_bf16(pf1, vfr, acc[1][f], 0, 0, 0);
          }
        }
      }
      __builtin_amdgcn_sched_barrier(0);
      __builtin_amdgcn_s_barrier();   // all waves done reading buf before it's overwritten
    }
    // ---- epilogue ----
#pragma unroll
    for (int r = 0; r < 2; ++r)
#pragma unroll
      for (int f = 0; f < 8; ++f)
#pragma unroll
        for (int i = 0; i < 4; ++i) {
          int row = qbase + r * 16 + lkg * 4 + i;
          int col = h * 128 + f * 16 + lrow;
          o[(size_t)row * 4096 + col] = f2bf(acc[r][f][i] / l_run[r][i]);
        }
  }
}

// ---------------------------------------------------------------
extern "C" void kernel_launch(void* const* d_in, const int* in_sizes, int n_in,
                              void* d_out, int out_size, void* d_ws, size_t ws_size,
                              hipStream_t stream) {
  (void)in_sizes; (void)n_in; (void)out_size; (void)ws_size;
  const float* hs   = (const float*)d_in[0];
  const float* Wqa  = (const float*)d_in[1];
  const float* qln  = (const float*)d_in[2];
  const float* Wqb  = (const float*)d_in[3];
  const float* Wkva = (const float*)d_in[4];
  const float* kvln = (const float*)d_in[5];
  const float* Wkvb = (const float*)d_in[6];
  const float* Wo   = (const float*)d_in[7];
  float* out = (float*)d_out;

  char* p = (char*)d_ws;
  size_t off = 0;
  auto carve = [&](size_t bytes) {
    char* r = p + off;
    off += (bytes + 255) & ~(size_t)255;
    return r;
  };
  u16* hs_bf = (u16*)carve((size_t)2048 * 4096 * 2);
  u16* WabT  = (u16*)carve((size_t)2112 * 4096 * 2);   // [0..1535]=WqaT, [1536..2111]=WkvaT
  u16* WqbT  = (u16*)carve((size_t)6144 * 1536 * 2);
  u16* WkvbT = (u16*)carve((size_t)8192 * 512 * 2);
  u16* WoT   = (u16*)carve((size_t)4096 * 4096 * 2);
  u16* fused = (u16*)carve((size_t)2048 * 2112 * 2);   // [qa | ckv] per row
  u16* qan   = (u16*)carve((size_t)2048 * 1536 * 2);
  u16* q     = (u16*)carve((size_t)2048 * 6144 * 2);
  u16* cn    = (u16*)carve((size_t)2048 * 512 * 2);
  u16* kv    = (u16*)carve((size_t)2048 * 8192 * 2);
  u16* qfb   = (u16*)carve((size_t)32 * 2048 * 192 * 2);
  u16* kfb   = (u16*)carve((size_t)32 * 2048 * 192 * 2);
  u16* vTb   = (u16*)carve((size_t)32 * 128 * 2048 * 2);
  u16* ob    = (u16*)carve((size_t)2048 * 4096 * 2);
  float* cost = (float*)carve((size_t)65536 * 4);
  float* sint = (float*)carve((size_t)65536 * 4);

  // --- prep: casts / transposes / tables ---
  cast_bf16_kernel<<<8192, 256, 0, stream>>>(hs, hs_bf, 2048 * 4096);
  transpose_cast_kernel<<<dim3(24, 64), 256, 0, stream>>>(Wqa, WabT, 4096, 1536);
  transpose_cast_kernel<<<dim3(9, 64), 256, 0, stream>>>(Wkva, WabT + (size_t)1536 * 4096, 4096, 576);
  transpose_cast_kernel<<<dim3(96, 24), 256, 0, stream>>>(Wqb, WqbT, 1536, 6144);
  transpose_cast_kernel<<<dim3(128, 8), 256, 0, stream>>>(Wkvb, WkvbT, 512, 8192);
  transpose_cast_kernel<<<dim3(64, 64), 256, 0, stream>>>(Wo, WoT, 4096, 4096);
  rope_table_kernel<<<256, 256, 0, stream>>>(cost, sint);

  // --- fused first-stage GEMM: [qa | ckv] = hs @ [Wqa | Wkva] ---
  gemm_bt_kernel<1><<<dim3(17, 16), 256, 0, stream>>>(hs_bf, WabT, fused, 2048, 2112, 4096);

  // --- norms ---
  rmsnorm_kernel<<<2048, 256, 0, stream>>>(fused, qln, qan, 1536, 2112, 1536);
  rmsnorm_kernel<<<2048, 256, 0, stream>>>(fused + 1536, kvln, cn, 512, 2112, 512);

  // --- second-stage GEMMs ---
  gemm_bt_kernel<1><<<dim3(48, 16), 256, 0, stream>>>(qan, WqbT, q, 2048, 6144, 1536);
  gemm_bt_kernel<1><<<dim3(64, 16), 256, 0, stream>>>(cn, WkvbT, kv, 2048, 8192, 512);

  // --- head-major layouts + RoPE (vectorized) ---
  build_qf_kernel<<<6144, 256, 0, stream>>>(q, cost, sint, qfb);
  build_kf_kernel<<<6144, 256, 0, stream>>>(kv, fused + 1536, cost, sint, kfb);
  vt_build_kernel<<<dim3(32, 2, 32), 256, 0, stream>>>(kv, vTb);

  // --- attention (256 blocks, 1/CU, dbuf + counted vmcnt) ---
  mla_attn_kernel<<<dim3(32, 8), 256, 0, stream>>>(qfb, kfb, vTb, ob);

  // --- output projection ---
  gemm_bt_kernel<0><<<dim3(32, 16), 256, 0, stream>>>(ob, WoT, out, 2048, 4096, 4096);
}

// Round 6
// 524.708 us; speedup vs baseline: 1.0348x; 1.0348x over previous
//
#include <hip/hip_runtime.h>

typedef unsigned short u16;
using bf16x8 = __attribute__((ext_vector_type(8))) __bf16;
using f32x4  = __attribute__((ext_vector_type(4))) float;
using s16x8  = __attribute__((ext_vector_type(8))) short;
using s16x4  = __attribute__((ext_vector_type(4))) short;

#define AS1 __attribute__((address_space(1)))
#define AS3 __attribute__((address_space(3)))

__device__ __forceinline__ void gload16(const u16* g, u16* l) {
  __builtin_amdgcn_global_load_lds((AS1 void*)(size_t)g, (AS3 void*)l, 16, 0, 0);
}

__device__ __forceinline__ u16 f2bf(float f) {
  unsigned u = __float_as_uint(f);
  u += 0x7fffu + ((u >> 16) & 1u);   // round-to-nearest-even
  return (u16)(u >> 16);
}
__device__ __forceinline__ float bf2f(u16 h) {
  return __uint_as_float(((unsigned)h) << 16);
}

// ---------------- elementwise f32 -> bf16 ----------------
__global__ __launch_bounds__(256) void cast_bf16_kernel(const float* __restrict__ x,
                                                        u16* __restrict__ y, int n) {
  int i = (blockIdx.x * 256 + threadIdx.x) * 4;
  if (i + 3 < n) {
    float4 v = *reinterpret_cast<const float4*>(x + i);
    s16x4 o;
    o[0] = (short)f2bf(v.x); o[1] = (short)f2bf(v.y);
    o[2] = (short)f2bf(v.z); o[3] = (short)f2bf(v.w);
    *reinterpret_cast<s16x4*>(y + i) = o;
  }
}

// ---------------- W [K][N] f32 -> WT [N][K] bf16 (64x64 tiles) ----------------
__global__ __launch_bounds__(256) void transpose_cast_kernel(const float* __restrict__ W,
                                                             u16* __restrict__ WT,
                                                             int K, int N) {
  __shared__ u16 tile[64][72];
  const int t = threadIdx.x;
  const int nb = blockIdx.x * 64, kb = blockIdx.y * 64;
  const int rr = t >> 3;        // 0..31
  const int cc = (t & 7) * 8;   // 0..56
#pragma unroll
  for (int pass = 0; pass < 2; ++pass) {
    const float* src = W + (size_t)(kb + pass * 32 + rr) * N + nb + cc;
    float4 a = *reinterpret_cast<const float4*>(src);
    float4 b = *reinterpret_cast<const float4*>(src + 4);
    u16* tr = &tile[pass * 32 + rr][cc];
    tr[0] = f2bf(a.x); tr[1] = f2bf(a.y); tr[2] = f2bf(a.z); tr[3] = f2bf(a.w);
    tr[4] = f2bf(b.x); tr[5] = f2bf(b.y); tr[6] = f2bf(b.z); tr[7] = f2bf(b.w);
  }
  __syncthreads();
#pragma unroll
  for (int pass = 0; pass < 2; ++pass) {
    s16x8 v;
#pragma unroll
    for (int j = 0; j < 8; ++j) v[j] = (short)tile[cc + j][pass * 32 + rr];
    *reinterpret_cast<s16x8*>(WT + (size_t)(nb + pass * 32 + rr) * K + kb + cc) = v;
  }
}

// ---------------- RMSNorm (bf16 in/out, f32 weight) ----------------
__global__ __launch_bounds__(256) void rmsnorm_kernel(const u16* __restrict__ x,
                                                      const float* __restrict__ w,
                                                      u16* __restrict__ y,
                                                      int R, int xs, int ys) {
  const int row = blockIdx.x, t = threadIdx.x;
  const u16* xr = x + (size_t)row * xs;
  float ss = 0.f;
  for (int i = t; i < R; i += 256) { float f = bf2f(xr[i]); ss += f * f; }
#pragma unroll
  for (int m = 32; m >= 1; m >>= 1) ss += __shfl_xor(ss, m);
  __shared__ float red[4];
  if ((t & 63) == 0) red[t >> 6] = ss;
  __syncthreads();
  float tot = red[0] + red[1] + red[2] + red[3];
  float r = rsqrtf(tot / (float)R + 1e-6f);
  u16* yr = y + (size_t)row * ys;
  for (int i = t; i < R; i += 256) yr[i] = f2bf(bf2f(xr[i]) * r * w[i]);
}

// ---------------- RoPE cos/sin table: [2048][32] each ----------------
__global__ __launch_bounds__(256) void rope_table_kernel(float* __restrict__ cost,
                                                         float* __restrict__ sint) {
  int idx = blockIdx.x * 256 + threadIdx.x;   // 65536
  int pos = idx >> 5, j = idx & 31;
  float inv = __expf(-(float)j * (9.210340371976184f / 32.0f));  // 10000^(-j/32)
  float f = (float)pos * inv;
  cost[idx] = cosf(f);
  sint[idx] = sinf(f);
}

// ---------------- qf build (vectorized): q [s][h*192] -> qf [h][s][192], RoPE + scale ----------------
__global__ __launch_bounds__(256) void build_qf_kernel(const u16* __restrict__ q,
                                                       const float* __restrict__ cost,
                                                       const float* __restrict__ sint,
                                                       u16* __restrict__ qf) {
  int tid = blockIdx.x * 256 + threadIdx.x;
  int o8 = tid * 8;
  if (o8 >= 32 * 2048 * 192) return;
  const float scale = 0.07216878364870323f;  // 192^-0.5 (folded into q)
  int c = (o8 % 192) >> 3;  // chunk 0..23
  int rest = o8 / 192;
  int s = rest & 2047, h = rest >> 11;
  const u16* qrow = q + ((size_t)s * 32 + h) * 192;
  s16x8 out;
  if (c < 16) {
    s16x8 v = *reinterpret_cast<const s16x8*>(qrow + c * 8);
#pragma unroll
    for (int j = 0; j < 8; ++j) out[j] = (short)f2bf(bf2f((u16)v[j]) * scale);
  } else {
    int j0 = c * 8 - 128;
    bool lo = j0 < 32;
    int jj0 = lo ? j0 : j0 - 32;
    s16x8 a = *reinterpret_cast<const s16x8*>(qrow + 128 + 2 * jj0);
    s16x8 b = *reinterpret_cast<const s16x8*>(qrow + 128 + 2 * jj0 + 8);
    float4 c0 = *reinterpret_cast<const float4*>(cost + s * 32 + jj0);
    float4 c1 = *reinterpret_cast<const float4*>(cost + s * 32 + jj0 + 4);
    float4 s0 = *reinterpret_cast<const float4*>(sint + s * 32 + jj0);
    float4 s1 = *reinterpret_cast<const float4*>(sint + s * 32 + jj0 + 4);
    float cs[8] = {c0.x, c0.y, c0.z, c0.w, c1.x, c1.y, c1.z, c1.w};
    float sn[8] = {s0.x, s0.y, s0.z, s0.w, s1.x, s1.y, s1.z, s1.w};
#pragma unroll
    for (int j = 0; j < 8; ++j) {
      float x0 = bf2f((u16)((j < 4) ? a[2 * j] : b[2 * j - 8]));
      float x1 = bf2f((u16)((j < 4) ? a[2 * j + 1] : b[2 * j - 7]));
      float v = lo ? (x0 * cs[j] - x1 * sn[j]) : (x1 * cs[j] + x0 * sn[j]);
      out[j] = (short)f2bf(v * scale);
    }
  }
  *reinterpret_cast<s16x8*>(qf + o8) = out;
}

// ---------------- kf build (vectorized): kv [s][h*256], ckv(stride 2112) -> kf [h][s][192] ----------------
__global__ __launch_bounds__(256) void build_kf_kernel(const u16* __restrict__ kv,
                                                       const u16* __restrict__ ckv,
                                                       const float* __restrict__ cost,
                                                       const float* __restrict__ sint,
                                                       u16* __restrict__ kf) {
  int tid = blockIdx.x * 256 + threadIdx.x;
  int o8 = tid * 8;
  if (o8 >= 32 * 2048 * 192) return;
  int c = (o8 % 192) >> 3;
  int rest = o8 / 192;
  int s = rest & 2047, h = rest >> 11;
  s16x8 out;
  if (c < 16) {
    out = *reinterpret_cast<const s16x8*>(kv + ((size_t)s * 32 + h) * 256 + c * 8);
  } else {
    int j0 = c * 8 - 128;
    bool lo = j0 < 32;
    int jj0 = lo ? j0 : j0 - 32;
    const u16* crow = ckv + (size_t)s * 2112 + 512;
    s16x8 a = *reinterpret_cast<const s16x8*>(crow + 2 * jj0);
    s16x8 b = *reinterpret_cast<const s16x8*>(crow + 2 * jj0 + 8);
    float4 c0 = *reinterpret_cast<const float4*>(cost + s * 32 + jj0);
    float4 c1 = *reinterpret_cast<const float4*>(cost + s * 32 + jj0 + 4);
    float4 s0 = *reinterpret_cast<const float4*>(sint + s * 32 + jj0);
    float4 s1 = *reinterpret_cast<const float4*>(sint + s * 32 + jj0 + 4);
    float cs[8] = {c0.x, c0.y, c0.z, c0.w, c1.x, c1.y, c1.z, c1.w};
    float sn[8] = {s0.x, s0.y, s0.z, s0.w, s1.x, s1.y, s1.z, s1.w};
#pragma unroll
    for (int j = 0; j < 8; ++j) {
      float x0 = bf2f((u16)((j < 4) ? a[2 * j] : b[2 * j - 8]));
      float x1 = bf2f((u16)((j < 4) ? a[2 * j + 1] : b[2 * j - 7]));
      float v = lo ? (x0 * cs[j] - x1 * sn[j]) : (x1 * cs[j] + x0 * sn[j]);
      out[j] = (short)f2bf(v);
    }
  }
  *reinterpret_cast<s16x8*>(kf + o8) = out;
}

// ---------------- vT build: kv [s][h*256+128+d] -> vT [h][128][2048] ----------------
__global__ __launch_bounds__(256) void vt_build_kernel(const u16* __restrict__ kv,
                                                       u16* __restrict__ vT) {
  __shared__ u16 tile[64][72];
  const int t = threadIdx.x;
  const int sb = blockIdx.x * 64, db = blockIdx.y * 64, h = blockIdx.z;
  const int rr = t >> 3, cc = (t & 7) * 8;
#pragma unroll
  for (int pass = 0; pass < 2; ++pass) {
    const u16* src = kv + (size_t)(sb + pass * 32 + rr) * 8192 + h * 256 + 128 + db + cc;
    s16x8 v = *reinterpret_cast<const s16x8*>(src);
#pragma unroll
    for (int j = 0; j < 8; ++j) tile[pass * 32 + rr][cc + j] = (u16)v[j];
  }
  __syncthreads();
#pragma unroll
  for (int pass = 0; pass < 2; ++pass) {
    s16x8 v;
#pragma unroll
    for (int j = 0; j < 8; ++j) v[j] = (short)tile[cc + j][pass * 32 + rr];
    *reinterpret_cast<s16x8*>(vT + ((size_t)h * 128 + db + pass * 32 + rr) * 2048 + sb + cc) = v;
  }
}

// ---------------- GEMM: C[M][N] = A[M][K](bf16) * BT[N][K](bf16)^T ----------------
// 128x128 tile, BK=64 (halves barrier pairs vs BK=32), 4 waves (2x2),
// global_load_lds staging. Frags loaded per-kk to keep VGPR pressure flat.
template <int OUT_BF16>
__global__ __launch_bounds__(256) void gemm_bt_kernel(const u16* __restrict__ A,
                                                      const u16* __restrict__ BT,
                                                      void* __restrict__ Cv,
                                                      int M, int N, int K) {
  __shared__ __align__(16) u16 As[128 * 64];
  __shared__ __align__(16) u16 Bs[128 * 64];
  const int t = threadIdx.x;
  const int lane = t & 63, wave = t >> 6;
  const int wr = wave >> 1, wc = wave & 1;
  const int row0 = blockIdx.y * 128, col0 = blockIdx.x * 128;
  const int srow = t >> 3;          // 0..31 (row within 32-row pass)
  const int sk = (t & 7) * 8;       // k offset within BK=64
  const int lrow = lane & 15, lkg = lane >> 4;
  const int aoff = (wr * 64 + lrow) * 64 + lkg * 8;
  const int boff = (wc * 64 + lrow) * 64 + lkg * 8;

  int brr[4];
  const int ldest = srow * 64 + sk;
#pragma unroll
  for (int pass = 0; pass < 4; ++pass) {
    int br = col0 + pass * 32 + srow;
    brr[pass] = (br > N - 1) ? (N - 1) : br;
  }

  f32x4 acc[4][4];
#pragma unroll
  for (int m = 0; m < 4; ++m)
#pragma unroll
    for (int n = 0; n < 4; ++n) acc[m][n] = 0.f;

  for (int k0 = 0; k0 < K; k0 += 64) {
#pragma unroll
    for (int pass = 0; pass < 4; ++pass) {
      gload16(A  + (size_t)(row0 + pass * 32 + srow) * K + k0 + sk, &As[pass * 2048 + ldest]);
      gload16(BT + (size_t)brr[pass] * K + k0 + sk,                 &Bs[pass * 2048 + ldest]);
    }
    __syncthreads();
#pragma unroll
    for (int kk = 0; kk < 2; ++kk) {
      bf16x8 af[4], bb[4];
#pragma unroll
      for (int m = 0; m < 4; ++m)
        af[m] = *reinterpret_cast<const bf16x8*>(&As[aoff + m * 1024 + kk * 32]);
#pragma unroll
      for (int n = 0; n < 4; ++n)
        bb[n] = *reinterpret_cast<const bf16x8*>(&Bs[boff + n * 1024 + kk * 32]);
#pragma unroll
      for (int m = 0; m < 4; ++m)
#pragma unroll
        for (int n = 0; n < 4; ++n)
          acc[m][n] = __builtin_amdgcn_mfma_f32_16x16x32_bf16(af[m], bb[n], acc[m][n], 0, 0, 0);
    }
    __syncthreads();
  }

#pragma unroll
  for (int m = 0; m < 4; ++m) {
#pragma unroll
    for (int n = 0; n < 4; ++n) {
      int col = col0 + wc * 64 + n * 16 + lrow;
      if (col < N) {
#pragma unroll
        for (int i = 0; i < 4; ++i) {
          int row = row0 + wr * 64 + m * 16 + lkg * 4 + i;
          size_t idx = (size_t)row * N + col;
          if (OUT_BF16) ((u16*)Cv)[idx] = f2bf(acc[m][n][i]);
          else          ((float*)Cv)[idx] = acc[m][n][i];
        }
      }
    }
  }
}

// ---------------- causal flash attention (paired + LDS-staged K/V, XCD head-pinned) ----------------
// grid (h=32, pair=16): bid = h + 32*pair -> bid%8 = h%8 pins each head's K/V to
// one XCD L2 (4 heads/XCD, ~5MB working set). 512 blocks = 2/CU (cross-block
// overlap hides staging). Block handles qb=pair and qb=31-pair (constant 33
// KV-64 iterations). 256 thr = 4 waves; wave w owns q rows qb*64+w*16..+16.
// K/V staged to LDS in fragment order via global_load_lds (rule #21: linear
// dest, per-lane global src carries permutation). ds_reads linear, conflict-free.
__global__ __launch_bounds__(256) void mla_attn_kernel(const u16* __restrict__ qf,
                                                       const u16* __restrict__ kf,
                                                       const u16* __restrict__ vT,
                                                       u16* __restrict__ o) {
  const int h = blockIdx.x, pair = blockIdx.y;
  const int t = threadIdx.x, wave = t >> 6, lane = t & 63;
  const int lrow = lane & 15, lkg = lane >> 4;
  __shared__ __align__(16) u16 Kt[24 * 512];   // (cg,kk): K[cg*16+l&15][kk*32+(l>>4)*8]
  __shared__ __align__(16) u16 Vt[16 * 512];   // (f,ck):  vT[f*16+l&15][ck*32+(l>>4)*8]
  __shared__ __align__(16) u16 Pl[4][16][72];

  // per-lane staging sources (wave w stages K rows cg=w, V d-rows f=2w,2w+1)
  const u16* ksrc0 = kf + ((size_t)h * 2048 + wave * 16 + lrow) * 192 + lkg * 8;
  const u16* vsrc0 = vT + ((size_t)h * 128 + wave * 32 + lrow) * 2048 + lkg * 8;

  for (int qq = 0; qq < 2; ++qq) {
    const int qb = qq ? (31 - pair) : pair;
    const int qbase = qb * 64 + wave * 16;

    bf16x8 qfr[6];
    const u16* qrow_ptr = qf + ((size_t)h * 2048 + qbase + lrow) * 192;
#pragma unroll
    for (int kk = 0; kk < 6; ++kk)
      qfr[kk] = *reinterpret_cast<const bf16x8*>(qrow_ptr + kk * 32 + lkg * 8);

    f32x4 acc_o[8];
#pragma unroll
    for (int f = 0; f < 8; ++f) acc_o[f] = 0.f;
    float m_run[4], l_run[4];
#pragma unroll
    for (int i = 0; i < 4; ++i) { m_run[i] = -__builtin_inff(); l_run[i] = 0.f; }

    const int kv_end = qb * 64 + 64;
    for (int kt = 0; kt < kv_end; kt += 64) {
      // ---- stage K tile (6 chunks: kk=0..5 for cg=wave) ----
      {
        const u16* ks = ksrc0 + (size_t)kt * 192;
#pragma unroll
        for (int kk = 0; kk < 6; ++kk)
          gload16(ks + kk * 32, &Kt[(wave * 6 + kk) * 512]);
        // ---- stage V tile (4 chunks: f=2w+(j>>1), ck=j&1) ----
#pragma unroll
        for (int j = 0; j < 4; ++j) {
          int fo = (j >> 1), ck = j & 1;
          gload16(vsrc0 + (size_t)fo * 16 * 2048 + kt + ck * 32,
                  &Vt[((wave * 2 + fo) * 2 + ck) * 512]);
        }
      }
      __syncthreads();   // drains vmcnt -> staged data visible to all waves

      // ---- S = Q K^T (16 x 64) from LDS ----
      f32x4 sv[4];
#pragma unroll
      for (int cg = 0; cg < 4; ++cg) sv[cg] = 0.f;
#pragma unroll
      for (int cg = 0; cg < 4; ++cg)
#pragma unroll
        for (int kk = 0; kk < 6; ++kk) {
          bf16x8 kfr = *reinterpret_cast<const bf16x8*>(&Kt[(cg * 6 + kk) * 512 + lane * 8]);
          sv[cg] = __builtin_amdgcn_mfma_f32_16x16x32_bf16(qfr[kk], kfr, sv[cg], 0, 0, 0);
        }

      // ---- causal mask: only the diagonal tile needs it ----
      const int qrow_b = qbase + lkg * 4;
      if (kt + 64 >= kv_end) {
#pragma unroll
        for (int cg = 0; cg < 4; ++cg) {
          int kvcol = kt + cg * 16 + lrow;
#pragma unroll
          for (int i = 0; i < 4; ++i)
            if (kvcol > qrow_b + i) sv[cg][i] = -__builtin_inff();
        }
      }
      // ---- online softmax (row stats live in 16-lane groups) ----
      float tmax[4], m_new[4], alpha[4], rsum[4], p[4][4];
#pragma unroll
      for (int i = 0; i < 4; ++i)
        tmax[i] = fmaxf(fmaxf(sv[0][i], sv[1][i]), fmaxf(sv[2][i], sv[3][i]));
#pragma unroll
      for (int m = 8; m >= 1; m >>= 1)
#pragma unroll
        for (int i = 0; i < 4; ++i) tmax[i] = fmaxf(tmax[i], __shfl_xor(tmax[i], m));
#pragma unroll
      for (int i = 0; i < 4; ++i) {
        m_new[i] = fmaxf(m_run[i], tmax[i]);
#pragma unroll
        for (int cg = 0; cg < 4; ++cg) p[cg][i] = __expf(sv[cg][i] - m_new[i]);
        rsum[i] = (p[0][i] + p[1][i]) + (p[2][i] + p[3][i]);
      }
#pragma unroll
      for (int m = 8; m >= 1; m >>= 1)
#pragma unroll
        for (int i = 0; i < 4; ++i) rsum[i] += __shfl_xor(rsum[i], m);
#pragma unroll
      for (int i = 0; i < 4; ++i) {
        alpha[i] = __expf(m_run[i] - m_new[i]);
        l_run[i] = l_run[i] * alpha[i] + rsum[i];
        m_run[i] = m_new[i];
      }
#pragma unroll
      for (int f = 0; f < 8; ++f)
#pragma unroll
        for (int i = 0; i < 4; ++i) acc_o[f][i] *= alpha[i];
      // ---- P -> bf16 -> per-wave LDS ----
#pragma unroll
      for (int cg = 0; cg < 4; ++cg)
#pragma unroll
        for (int i = 0; i < 4; ++i)
          Pl[wave][lkg * 4 + i][cg * 16 + lrow] = f2bf(p[cg][i]);
      // ---- O += P V (V from LDS) ----
#pragma unroll
      for (int ck = 0; ck < 2; ++ck) {
        bf16x8 pf = *reinterpret_cast<const bf16x8*>(&Pl[wave][lrow][ck * 32 + lkg * 8]);
#pragma unroll
        for (int f = 0; f < 8; ++f) {
          bf16x8 vfr = *reinterpret_cast<const bf16x8*>(&Vt[(f * 2 + ck) * 512 + lane * 8]);
          acc_o[f] = __builtin_amdgcn_mfma_f32_16x16x32_bf16(pf, vfr, acc_o[f], 0, 0, 0);
        }
      }
      __syncthreads();   // all waves done reading Kt/Vt before next stage
    }
    // ---- epilogue: divide by l, store o[s][h*128+vd] ----
#pragma unroll
    for (int f = 0; f < 8; ++f)
#pragma unroll
      for (int i = 0; i < 4; ++i) {
        int row = qbase + lkg * 4 + i;
        int col = h * 128 + f * 16 + lrow;
        o[(size_t)row * 4096 + col] = f2bf(acc_o[f][i] / l_run[i]);
      }
  }
}

// ---------------------------------------------------------------
extern "C" void kernel_launch(void* const* d_in, const int* in_sizes, int n_in,
                              void* d_out, int out_size, void* d_ws, size_t ws_size,
                              hipStream_t stream) {
  (void)in_sizes; (void)n_in; (void)out_size; (void)ws_size;
  const float* hs   = (const float*)d_in[0];
  const float* Wqa  = (const float*)d_in[1];
  const float* qln  = (const float*)d_in[2];
  const float* Wqb  = (const float*)d_in[3];
  const float* Wkva = (const float*)d_in[4];
  const float* kvln = (const float*)d_in[5];
  const float* Wkvb = (const float*)d_in[6];
  const float* Wo   = (const float*)d_in[7];
  float* out = (float*)d_out;

  char* p = (char*)d_ws;
  size_t off = 0;
  auto carve = [&](size_t bytes) {
    char* r = p + off;
    off += (bytes + 255) & ~(size_t)255;
    return r;
  };
  u16* hs_bf = (u16*)carve((size_t)2048 * 4096 * 2);
  u16* WabT  = (u16*)carve((size_t)2112 * 4096 * 2);   // [0..1535]=WqaT, [1536..2111]=WkvaT
  u16* WqbT  = (u16*)carve((size_t)6144 * 1536 * 2);
  u16* WkvbT = (u16*)carve((size_t)8192 * 512 * 2);
  u16* WoT   = (u16*)carve((size_t)4096 * 4096 * 2);
  u16* fused = (u16*)carve((size_t)2048 * 2112 * 2);   // [qa | ckv] per row
  u16* qan   = (u16*)carve((size_t)2048 * 1536 * 2);
  u16* q     = (u16*)carve((size_t)2048 * 6144 * 2);
  u16* cn    = (u16*)carve((size_t)2048 * 512 * 2);
  u16* kv    = (u16*)carve((size_t)2048 * 8192 * 2);
  u16* qfb   = (u16*)carve((size_t)32 * 2048 * 192 * 2);
  u16* kfb   = (u16*)carve((size_t)32 * 2048 * 192 * 2);
  u16* vTb   = (u16*)carve((size_t)32 * 128 * 2048 * 2);
  u16* ob    = (u16*)carve((size_t)2048 * 4096 * 2);
  float* cost = (float*)carve((size_t)65536 * 4);
  float* sint = (float*)carve((size_t)65536 * 4);

  // --- prep: casts / transposes / tables ---
  cast_bf16_kernel<<<8192, 256, 0, stream>>>(hs, hs_bf, 2048 * 4096);
  transpose_cast_kernel<<<dim3(24, 64), 256, 0, stream>>>(Wqa, WabT, 4096, 1536);
  transpose_cast_kernel<<<dim3(9, 64), 256, 0, stream>>>(Wkva, WabT + (size_t)1536 * 4096, 4096, 576);
  transpose_cast_kernel<<<dim3(96, 24), 256, 0, stream>>>(Wqb, WqbT, 1536, 6144);
  transpose_cast_kernel<<<dim3(128, 8), 256, 0, stream>>>(Wkvb, WkvbT, 512, 8192);
  transpose_cast_kernel<<<dim3(64, 64), 256, 0, stream>>>(Wo, WoT, 4096, 4096);
  rope_table_kernel<<<256, 256, 0, stream>>>(cost, sint);

  // --- fused first-stage GEMM: [qa | ckv] = hs @ [Wqa | Wkva] ---
  gemm_bt_kernel<1><<<dim3(17, 16), 256, 0, stream>>>(hs_bf, WabT, fused, 2048, 2112, 4096);

  // --- norms ---
  rmsnorm_kernel<<<2048, 256, 0, stream>>>(fused, qln, qan, 1536, 2112, 1536);
  rmsnorm_kernel<<<2048, 256, 0, stream>>>(fused + 1536, kvln, cn, 512, 2112, 512);

  // --- second-stage GEMMs ---
  gemm_bt_kernel<1><<<dim3(48, 16), 256, 0, stream>>>(qan, WqbT, q, 2048, 6144, 1536);
  gemm_bt_kernel<1><<<dim3(64, 16), 256, 0, stream>>>(cn, WkvbT, kv, 2048, 8192, 512);

  // --- head-major layouts + RoPE (vectorized) ---
  build_qf_kernel<<<6144, 256, 0, stream>>>(q, cost, sint, qfb);
  build_kf_kernel<<<6144, 256, 0, stream>>>(kv, fused + 1536, cost, sint, kfb);
  vt_build_kernel<<<dim3(32, 2, 32), 256, 0, stream>>>(kv, vTb);

  // --- attention (512 blocks, 2/CU, head-pinned XCD, paired) ---
  mla_attn_kernel<<<dim3(32, 16), 256, 0, stream>>>(qfb, kfb, vTb, ob);

  // --- output projection ---
  gemm_bt_kernel<0><<<dim3(32, 16), 256, 0, stream>>>(ob, WoT, out, 2048, 4096, 4096);
}

// Round 7
// 430.230 us; speedup vs baseline: 1.2621x; 1.2196x over previous
//
#include <hip/hip_runtime.h>

typedef unsigned short u16;
using bf16x8 = __attribute__((ext_vector_type(8))) __bf16;
using f32x4  = __attribute__((ext_vector_type(4))) float;
using s16x8  = __attribute__((ext_vector_type(8))) short;
using s16x4  = __attribute__((ext_vector_type(4))) short;

#define AS1 __attribute__((address_space(1)))
#define AS3 __attribute__((address_space(3)))

__device__ __forceinline__ void gload16(const u16* g, u16* l) {
  __builtin_amdgcn_global_load_lds((AS1 void*)(size_t)g, (AS3 void*)l, 16, 0, 0);
}

__device__ __forceinline__ u16 f2bf(float f) {
  unsigned u = __float_as_uint(f);
  u += 0x7fffu + ((u >> 16) & 1u);   // round-to-nearest-even
  return (u16)(u >> 16);
}
__device__ __forceinline__ float bf2f(u16 h) {
  return __uint_as_float(((unsigned)h) << 16);
}

// ---------------- elementwise f32 -> bf16 ----------------
__global__ __launch_bounds__(256) void cast_bf16_kernel(const float* __restrict__ x,
                                                        u16* __restrict__ y, int n) {
  int i = (blockIdx.x * 256 + threadIdx.x) * 4;
  if (i + 3 < n) {
    float4 v = *reinterpret_cast<const float4*>(x + i);
    s16x4 o;
    o[0] = (short)f2bf(v.x); o[1] = (short)f2bf(v.y);
    o[2] = (short)f2bf(v.z); o[3] = (short)f2bf(v.w);
    *reinterpret_cast<s16x4*>(y + i) = o;
  }
}

// ---------------- W [K][N] f32 -> WT [N][K] bf16 (64x64 tiles) ----------------
__global__ __launch_bounds__(256) void transpose_cast_kernel(const float* __restrict__ W,
                                                             u16* __restrict__ WT,
                                                             int K, int N) {
  __shared__ u16 tile[64][72];
  const int t = threadIdx.x;
  const int nb = blockIdx.x * 64, kb = blockIdx.y * 64;
  const int rr = t >> 3;        // 0..31
  const int cc = (t & 7) * 8;   // 0..56
#pragma unroll
  for (int pass = 0; pass < 2; ++pass) {
    const float* src = W + (size_t)(kb + pass * 32 + rr) * N + nb + cc;
    float4 a = *reinterpret_cast<const float4*>(src);
    float4 b = *reinterpret_cast<const float4*>(src + 4);
    u16* tr = &tile[pass * 32 + rr][cc];
    tr[0] = f2bf(a.x); tr[1] = f2bf(a.y); tr[2] = f2bf(a.z); tr[3] = f2bf(a.w);
    tr[4] = f2bf(b.x); tr[5] = f2bf(b.y); tr[6] = f2bf(b.z); tr[7] = f2bf(b.w);
  }
  __syncthreads();
#pragma unroll
  for (int pass = 0; pass < 2; ++pass) {
    s16x8 v;
#pragma unroll
    for (int j = 0; j < 8; ++j) v[j] = (short)tile[cc + j][pass * 32 + rr];
    *reinterpret_cast<s16x8*>(WT + (size_t)(nb + pass * 32 + rr) * K + kb + cc) = v;
  }
}

// ---------------- RMSNorm (bf16 in/out, f32 weight) ----------------
__global__ __launch_bounds__(256) void rmsnorm_kernel(const u16* __restrict__ x,
                                                      const float* __restrict__ w,
                                                      u16* __restrict__ y,
                                                      int R, int xs, int ys) {
  const int row = blockIdx.x, t = threadIdx.x;
  const u16* xr = x + (size_t)row * xs;
  float ss = 0.f;
  for (int i = t; i < R; i += 256) { float f = bf2f(xr[i]); ss += f * f; }
#pragma unroll
  for (int m = 32; m >= 1; m >>= 1) ss += __shfl_xor(ss, m);
  __shared__ float red[4];
  if ((t & 63) == 0) red[t >> 6] = ss;
  __syncthreads();
  float tot = red[0] + red[1] + red[2] + red[3];
  float r = rsqrtf(tot / (float)R + 1e-6f);
  u16* yr = y + (size_t)row * ys;
  for (int i = t; i < R; i += 256) yr[i] = f2bf(bf2f(xr[i]) * r * w[i]);
}

// ---------------- RoPE cos/sin table: [2048][32] each ----------------
__global__ __launch_bounds__(256) void rope_table_kernel(float* __restrict__ cost,
                                                         float* __restrict__ sint) {
  int idx = blockIdx.x * 256 + threadIdx.x;   // 65536
  int pos = idx >> 5, j = idx & 31;
  float inv = __expf(-(float)j * (9.210340371976184f / 32.0f));  // 10000^(-j/32)
  float f = (float)pos * inv;
  cost[idx] = cosf(f);
  sint[idx] = sinf(f);
}

// ---------------- qf build (vectorized): q [s][h*192] -> qf [h][s][192], RoPE + scale ----------------
__global__ __launch_bounds__(256) void build_qf_kernel(const u16* __restrict__ q,
                                                       const float* __restrict__ cost,
                                                       const float* __restrict__ sint,
                                                       u16* __restrict__ qf) {
  int tid = blockIdx.x * 256 + threadIdx.x;
  int o8 = tid * 8;
  if (o8 >= 32 * 2048 * 192) return;
  const float scale = 0.07216878364870323f;  // 192^-0.5 (folded into q)
  int c = (o8 % 192) >> 3;  // chunk 0..23
  int rest = o8 / 192;
  int s = rest & 2047, h = rest >> 11;
  const u16* qrow = q + ((size_t)s * 32 + h) * 192;
  s16x8 out;
  if (c < 16) {
    s16x8 v = *reinterpret_cast<const s16x8*>(qrow + c * 8);
#pragma unroll
    for (int j = 0; j < 8; ++j) out[j] = (short)f2bf(bf2f((u16)v[j]) * scale);
  } else {
    int j0 = c * 8 - 128;
    bool lo = j0 < 32;
    int jj0 = lo ? j0 : j0 - 32;
    s16x8 a = *reinterpret_cast<const s16x8*>(qrow + 128 + 2 * jj0);
    s16x8 b = *reinterpret_cast<const s16x8*>(qrow + 128 + 2 * jj0 + 8);
    float4 c0 = *reinterpret_cast<const float4*>(cost + s * 32 + jj0);
    float4 c1 = *reinterpret_cast<const float4*>(cost + s * 32 + jj0 + 4);
    float4 s0 = *reinterpret_cast<const float4*>(sint + s * 32 + jj0);
    float4 s1 = *reinterpret_cast<const float4*>(sint + s * 32 + jj0 + 4);
    float cs[8] = {c0.x, c0.y, c0.z, c0.w, c1.x, c1.y, c1.z, c1.w};
    float sn[8] = {s0.x, s0.y, s0.z, s0.w, s1.x, s1.y, s1.z, s1.w};
#pragma unroll
    for (int j = 0; j < 8; ++j) {
      float x0 = bf2f((u16)((j < 4) ? a[2 * j] : b[2 * j - 8]));
      float x1 = bf2f((u16)((j < 4) ? a[2 * j + 1] : b[2 * j - 7]));
      float v = lo ? (x0 * cs[j] - x1 * sn[j]) : (x1 * cs[j] + x0 * sn[j]);
      out[j] = (short)f2bf(v * scale);
    }
  }
  *reinterpret_cast<s16x8*>(qf + o8) = out;
}

// ---------------- kf build (vectorized): kv [s][h*256], ckv(stride 2112) -> kf [h][s][192] ----------------
__global__ __launch_bounds__(256) void build_kf_kernel(const u16* __restrict__ kv,
                                                       const u16* __restrict__ ckv,
                                                       const float* __restrict__ cost,
                                                       const float* __restrict__ sint,
                                                       u16* __restrict__ kf) {
  int tid = blockIdx.x * 256 + threadIdx.x;
  int o8 = tid * 8;
  if (o8 >= 32 * 2048 * 192) return;
  int c = (o8 % 192) >> 3;
  int rest = o8 / 192;
  int s = rest & 2047, h = rest >> 11;
  s16x8 out;
  if (c < 16) {
    out = *reinterpret_cast<const s16x8*>(kv + ((size_t)s * 32 + h) * 256 + c * 8);
  } else {
    int j0 = c * 8 - 128;
    bool lo = j0 < 32;
    int jj0 = lo ? j0 : j0 - 32;
    const u16* crow = ckv + (size_t)s * 2112 + 512;
    s16x8 a = *reinterpret_cast<const s16x8*>(crow + 2 * jj0);
    s16x8 b = *reinterpret_cast<const s16x8*>(crow + 2 * jj0 + 8);
    float4 c0 = *reinterpret_cast<const float4*>(cost + s * 32 + jj0);
    float4 c1 = *reinterpret_cast<const float4*>(cost + s * 32 + jj0 + 4);
    float4 s0 = *reinterpret_cast<const float4*>(sint + s * 32 + jj0);
    float4 s1 = *reinterpret_cast<const float4*>(sint + s * 32 + jj0 + 4);
    float cs[8] = {c0.x, c0.y, c0.z, c0.w, c1.x, c1.y, c1.z, c1.w};
    float sn[8] = {s0.x, s0.y, s0.z, s0.w, s1.x, s1.y, s1.z, s1.w};
#pragma unroll
    for (int j = 0; j < 8; ++j) {
      float x0 = bf2f((u16)((j < 4) ? a[2 * j] : b[2 * j - 8]));
      float x1 = bf2f((u16)((j < 4) ? a[2 * j + 1] : b[2 * j - 7]));
      float v = lo ? (x0 * cs[j] - x1 * sn[j]) : (x1 * cs[j] + x0 * sn[j]);
      out[j] = (short)f2bf(v);
    }
  }
  *reinterpret_cast<s16x8*>(kf + o8) = out;
}

// ---------------- vT build: kv [s][h*256+128+d] -> vT [h][128][2048] ----------------
__global__ __launch_bounds__(256) void vt_build_kernel(const u16* __restrict__ kv,
                                                       u16* __restrict__ vT) {
  __shared__ u16 tile[64][72];
  const int t = threadIdx.x;
  const int sb = blockIdx.x * 64, db = blockIdx.y * 64, h = blockIdx.z;
  const int rr = t >> 3, cc = (t & 7) * 8;
#pragma unroll
  for (int pass = 0; pass < 2; ++pass) {
    const u16* src = kv + (size_t)(sb + pass * 32 + rr) * 8192 + h * 256 + 128 + db + cc;
    s16x8 v = *reinterpret_cast<const s16x8*>(src);
#pragma unroll
    for (int j = 0; j < 8; ++j) tile[pass * 32 + rr][cc + j] = (u16)v[j];
  }
  __syncthreads();
#pragma unroll
  for (int pass = 0; pass < 2; ++pass) {
    s16x8 v;
#pragma unroll
    for (int j = 0; j < 8; ++j) v[j] = (short)tile[cc + j][pass * 32 + rr];
    *reinterpret_cast<s16x8*>(vT + ((size_t)h * 128 + db + pass * 32 + rr) * 2048 + sb + cc) = v;
  }
}

// ---------------- GEMM v3: C[M][N] = A[M][K](bf16) * BT[N][K](bf16)^T ----------------
// 128x128 tile, BK=32, 4 waves (2x2). 4-deep LDS pipeline (4 x 16KB), prefetch
// distance 3, ONE raw s_barrier/iter with counted vmcnt(8) (T4 - never drain to 0
// in main loop), XOR-swizzled LDS (T2: el_off ^= (el_off>>3)&0x18; staging uses
// pre-swizzled source lane' = lane ^ ((lane>>3)&3), rule #21), setprio MFMA (T5).
// Race safety: tile t+3 writes buf[(t-1)%4]; tile t-1's ds_reads are consumed
// (lgkmcnt-drained before its MFMAs) before barrier t; staging issues after.
template <int OUT_BF16>
__global__ __launch_bounds__(256) void gemm_v3_kernel(const u16* __restrict__ A,
                                                      const u16* __restrict__ BT,
                                                      void* __restrict__ Cv,
                                                      int M, int N, int K) {
  __shared__ __align__(16) u16 S[4 * 8192];   // buf b: A at b*8192, B at b*8192+4096 (elems)
  const int t0 = threadIdx.x;
  const int lane = t0 & 63, wave = t0 >> 6;
  const int wr = wave >> 1, wc = wave & 1;
  const int row0 = blockIdx.y * 128, col0 = blockIdx.x * 128;
  const int lrow = lane & 15, lkg = lane >> 4;

  // staging source permutation (inverse swizzle on the global side)
  const int lp = lane ^ ((lane >> 3) & 3);
  const int srow_off = lp >> 2;       // row within 16-row chunk
  const int skel = (lp & 3) * 8;      // k element within BK=32
  const int c0 = wave * 2, c1 = c0 + 1;   // this wave's chunk ids (0..7)
  const int arow_c0 = row0 + c0 * 16 + srow_off;
  const int arow_c1 = row0 + c1 * 16 + srow_off;
  int brow_c0 = col0 + c0 * 16 + srow_off; if (brow_c0 > N - 1) brow_c0 = N - 1;
  int brow_c1 = col0 + c1 * 16 + srow_off; if (brow_c1 > N - 1) brow_c1 = N - 1;

  // read-side swizzled element offsets
  int aoff[4], boff[4];
#pragma unroll
  for (int m = 0; m < 4; ++m) {
    int r = wr * 64 + m * 16 + lrow;
    int off = r * 32 + lkg * 8;
    aoff[m] = off ^ ((off >> 3) & 0x18);
    r = wc * 64 + m * 16 + lrow;
    off = r * 32 + lkg * 8;
    boff[m] = off ^ ((off >> 3) & 0x18);
  }

  const int NT = K >> 5;

  // prologue: stage tiles 0,1,2
#pragma unroll
  for (int pt = 0; pt < 3; ++pt) {
    u16* ab = &S[pt * 8192];
    const int kb = pt * 32 + skel;
    gload16(A  + (size_t)arow_c0 * K + kb, ab + c0 * 512);
    gload16(A  + (size_t)arow_c1 * K + kb, ab + c1 * 512);
    gload16(BT + (size_t)brow_c0 * K + kb, ab + 4096 + c0 * 512);
    gload16(BT + (size_t)brow_c1 * K + kb, ab + 4096 + c1 * 512);
  }

  f32x4 acc[4][4];
#pragma unroll
  for (int m = 0; m < 4; ++m)
#pragma unroll
    for (int n = 0; n < 4; ++n) acc[m][n] = 0.f;

  for (int t = 0; t < NT; ++t) {
    if (t + 2 < NT)      asm volatile("s_waitcnt vmcnt(8)" ::: "memory");
    else if (t + 1 < NT) asm volatile("s_waitcnt vmcnt(4)" ::: "memory");
    else                 asm volatile("s_waitcnt vmcnt(0)" ::: "memory");
    __builtin_amdgcn_s_barrier();
    __builtin_amdgcn_sched_barrier(0);

    const u16* ab = &S[(t & 3) * 8192];
    bf16x8 af[4], bb[4];
#pragma unroll
    for (int m = 0; m < 4; ++m)
      af[m] = *reinterpret_cast<const bf16x8*>(ab + aoff[m]);
#pragma unroll
    for (int n = 0; n < 4; ++n)
      bb[n] = *reinterpret_cast<const bf16x8*>(ab + 4096 + boff[n]);

    if (t + 3 < NT) {   // stage tile t+3 into buf (t+3)&3
      u16* sb = &S[((t + 3) & 3) * 8192];
      const int kb = (t + 3) * 32 + skel;
      gload16(A  + (size_t)arow_c0 * K + kb, sb + c0 * 512);
      gload16(A  + (size_t)arow_c1 * K + kb, sb + c1 * 512);
      gload16(BT + (size_t)brow_c0 * K + kb, sb + 4096 + c0 * 512);
      gload16(BT + (size_t)brow_c1 * K + kb, sb + 4096 + c1 * 512);
    }

    __builtin_amdgcn_s_setprio(1);
#pragma unroll
    for (int m = 0; m < 4; ++m)
#pragma unroll
      for (int n = 0; n < 4; ++n)
        acc[m][n] = __builtin_amdgcn_mfma_f32_16x16x32_bf16(af[m], bb[n], acc[m][n], 0, 0, 0);
    __builtin_amdgcn_s_setprio(0);
  }

#pragma unroll
  for (int m = 0; m < 4; ++m) {
#pragma unroll
    for (int n = 0; n < 4; ++n) {
      int col = col0 + wc * 64 + n * 16 + lrow;
      if (col < N) {
#pragma unroll
        for (int i = 0; i < 4; ++i) {
          int row = row0 + wr * 64 + m * 16 + lkg * 4 + i;
          size_t idx = (size_t)row * N + col;
          if (OUT_BF16) ((u16*)Cv)[idx] = f2bf(acc[m][n][i]);
          else          ((float*)Cv)[idx] = acc[m][n][i];
        }
      }
    }
  }
}

// ---------------- causal flash attention (paired + LDS-staged K/V, XCD head-pinned) ----------------
// grid (h=32, pair=16): bid%8 = h%8 pins each head's K/V to one XCD L2.
// 512 blocks = 2/CU (cross-block overlap hides staging). Block handles qb=pair
// and qb=31-pair (constant 33 KV-64 iterations). 256 thr = 4 waves; wave w owns
// q rows qb*64+w*16..+16. K/V staged to LDS in fragment order via global_load_lds.
__global__ __launch_bounds__(256) void mla_attn_kernel(const u16* __restrict__ qf,
                                                       const u16* __restrict__ kf,
                                                       const u16* __restrict__ vT,
                                                       u16* __restrict__ o) {
  const int h = blockIdx.x, pair = blockIdx.y;
  const int t = threadIdx.x, wave = t >> 6, lane = t & 63;
  const int lrow = lane & 15, lkg = lane >> 4;
  __shared__ __align__(16) u16 Kt[24 * 512];   // (cg,kk): K[cg*16+l&15][kk*32+(l>>4)*8]
  __shared__ __align__(16) u16 Vt[16 * 512];   // (f,ck):  vT[f*16+l&15][ck*32+(l>>4)*8]
  __shared__ __align__(16) u16 Pl[4][16][72];

  const u16* ksrc0 = kf + ((size_t)h * 2048 + wave * 16 + lrow) * 192 + lkg * 8;
  const u16* vsrc0 = vT + ((size_t)h * 128 + wave * 32 + lrow) * 2048 + lkg * 8;

  for (int qq = 0; qq < 2; ++qq) {
    const int qb = qq ? (31 - pair) : pair;
    const int qbase = qb * 64 + wave * 16;

    bf16x8 qfr[6];
    const u16* qrow_ptr = qf + ((size_t)h * 2048 + qbase + lrow) * 192;
#pragma unroll
    for (int kk = 0; kk < 6; ++kk)
      qfr[kk] = *reinterpret_cast<const bf16x8*>(qrow_ptr + kk * 32 + lkg * 8);

    f32x4 acc_o[8];
#pragma unroll
    for (int f = 0; f < 8; ++f) acc_o[f] = 0.f;
    float m_run[4], l_run[4];
#pragma unroll
    for (int i = 0; i < 4; ++i) { m_run[i] = -__builtin_inff(); l_run[i] = 0.f; }

    const int kv_end = qb * 64 + 64;
    for (int kt = 0; kt < kv_end; kt += 64) {
      {
        const u16* ks = ksrc0 + (size_t)kt * 192;
#pragma unroll
        for (int kk = 0; kk < 6; ++kk)
          gload16(ks + kk * 32, &Kt[(wave * 6 + kk) * 512]);
#pragma unroll
        for (int j = 0; j < 4; ++j) {
          int fo = (j >> 1), ck = j & 1;
          gload16(vsrc0 + (size_t)fo * 16 * 2048 + kt + ck * 32,
                  &Vt[((wave * 2 + fo) * 2 + ck) * 512]);
        }
      }
      __syncthreads();

      f32x4 sv[4];
#pragma unroll
      for (int cg = 0; cg < 4; ++cg) sv[cg] = 0.f;
#pragma unroll
      for (int cg = 0; cg < 4; ++cg)
#pragma unroll
        for (int kk = 0; kk < 6; ++kk) {
          bf16x8 kfr = *reinterpret_cast<const bf16x8*>(&Kt[(cg * 6 + kk) * 512 + lane * 8]);
          sv[cg] = __builtin_amdgcn_mfma_f32_16x16x32_bf16(qfr[kk], kfr, sv[cg], 0, 0, 0);
        }

      const int qrow_b = qbase + lkg * 4;
      if (kt + 64 >= kv_end) {
#pragma unroll
        for (int cg = 0; cg < 4; ++cg) {
          int kvcol = kt + cg * 16 + lrow;
#pragma unroll
          for (int i = 0; i < 4; ++i)
            if (kvcol > qrow_b + i) sv[cg][i] = -__builtin_inff();
        }
      }
      float tmax[4], m_new[4], alpha[4], rsum[4], p[4][4];
#pragma unroll
      for (int i = 0; i < 4; ++i)
        tmax[i] = fmaxf(fmaxf(sv[0][i], sv[1][i]), fmaxf(sv[2][i], sv[3][i]));
#pragma unroll
      for (int m = 8; m >= 1; m >>= 1)
#pragma unroll
        for (int i = 0; i < 4; ++i) tmax[i] = fmaxf(tmax[i], __shfl_xor(tmax[i], m));
#pragma unroll
      for (int i = 0; i < 4; ++i) {
        m_new[i] = fmaxf(m_run[i], tmax[i]);
#pragma unroll
        for (int cg = 0; cg < 4; ++cg) p[cg][i] = __expf(sv[cg][i] - m_new[i]);
        rsum[i] = (p[0][i] + p[1][i]) + (p[2][i] + p[3][i]);
      }
#pragma unroll
      for (int m = 8; m >= 1; m >>= 1)
#pragma unroll
        for (int i = 0; i < 4; ++i) rsum[i] += __shfl_xor(rsum[i], m);
#pragma unroll
      for (int i = 0; i < 4; ++i) {
        alpha[i] = __expf(m_run[i] - m_new[i]);
        l_run[i] = l_run[i] * alpha[i] + rsum[i];
        m_run[i] = m_new[i];
      }
#pragma unroll
      for (int f = 0; f < 8; ++f)
#pragma unroll
        for (int i = 0; i < 4; ++i) acc_o[f][i] *= alpha[i];
#pragma unroll
      for (int cg = 0; cg < 4; ++cg)
#pragma unroll
        for (int i = 0; i < 4; ++i)
          Pl[wave][lkg * 4 + i][cg * 16 + lrow] = f2bf(p[cg][i]);
#pragma unroll
      for (int ck = 0; ck < 2; ++ck) {
        bf16x8 pf = *reinterpret_cast<const bf16x8*>(&Pl[wave][lrow][ck * 32 + lkg * 8]);
#pragma unroll
        for (int f = 0; f < 8; ++f) {
          bf16x8 vfr = *reinterpret_cast<const bf16x8*>(&Vt[(f * 2 + ck) * 512 + lane * 8]);
          acc_o[f] = __builtin_amdgcn_mfma_f32_16x16x32_bf16(pf, vfr, acc_o[f], 0, 0, 0);
        }
      }
      __syncthreads();
    }
#pragma unroll
    for (int f = 0; f < 8; ++f)
#pragma unroll
      for (int i = 0; i < 4; ++i) {
        int row = qbase + lkg * 4 + i;
        int col = h * 128 + f * 16 + lrow;
        o[(size_t)row * 4096 + col] = f2bf(acc_o[f][i] / l_run[i]);
      }
  }
}

// ---------------------------------------------------------------
extern "C" void kernel_launch(void* const* d_in, const int* in_sizes, int n_in,
                              void* d_out, int out_size, void* d_ws, size_t ws_size,
                              hipStream_t stream) {
  (void)in_sizes; (void)n_in; (void)out_size; (void)ws_size;
  const float* hs   = (const float*)d_in[0];
  const float* Wqa  = (const float*)d_in[1];
  const float* qln  = (const float*)d_in[2];
  const float* Wqb  = (const float*)d_in[3];
  const float* Wkva = (const float*)d_in[4];
  const float* kvln = (const float*)d_in[5];
  const float* Wkvb = (const float*)d_in[6];
  const float* Wo   = (const float*)d_in[7];
  float* out = (float*)d_out;

  char* p = (char*)d_ws;
  size_t off = 0;
  auto carve = [&](size_t bytes) {
    char* r = p + off;
    off += (bytes + 255) & ~(size_t)255;
    return r;
  };
  u16* hs_bf = (u16*)carve((size_t)2048 * 4096 * 2);
  u16* WabT  = (u16*)carve((size_t)2112 * 4096 * 2);   // [0..1535]=WqaT, [1536..2111]=WkvaT
  u16* WqbT  = (u16*)carve((size_t)6144 * 1536 * 2);
  u16* WkvbT = (u16*)carve((size_t)8192 * 512 * 2);
  u16* WoT   = (u16*)carve((size_t)4096 * 4096 * 2);
  u16* fused = (u16*)carve((size_t)2048 * 2112 * 2);   // [qa | ckv] per row
  u16* qan   = (u16*)carve((size_t)2048 * 1536 * 2);
  u16* q     = (u16*)carve((size_t)2048 * 6144 * 2);
  u16* cn    = (u16*)carve((size_t)2048 * 512 * 2);
  u16* kv    = (u16*)carve((size_t)2048 * 8192 * 2);
  u16* qfb   = (u16*)carve((size_t)32 * 2048 * 192 * 2);
  u16* kfb   = (u16*)carve((size_t)32 * 2048 * 192 * 2);
  u16* vTb   = (u16*)carve((size_t)32 * 128 * 2048 * 2);
  u16* ob    = (u16*)carve((size_t)2048 * 4096 * 2);
  float* cost = (float*)carve((size_t)65536 * 4);
  float* sint = (float*)carve((size_t)65536 * 4);

  // --- prep: casts / transposes / tables ---
  cast_bf16_kernel<<<8192, 256, 0, stream>>>(hs, hs_bf, 2048 * 4096);
  transpose_cast_kernel<<<dim3(24, 64), 256, 0, stream>>>(Wqa, WabT, 4096, 1536);
  transpose_cast_kernel<<<dim3(9, 64), 256, 0, stream>>>(Wkva, WabT + (size_t)1536 * 4096, 4096, 576);
  transpose_cast_kernel<<<dim3(96, 24), 256, 0, stream>>>(Wqb, WqbT, 1536, 6144);
  transpose_cast_kernel<<<dim3(128, 8), 256, 0, stream>>>(Wkvb, WkvbT, 512, 8192);
  transpose_cast_kernel<<<dim3(64, 64), 256, 0, stream>>>(Wo, WoT, 4096, 4096);
  rope_table_kernel<<<256, 256, 0, stream>>>(cost, sint);

  // --- fused first-stage GEMM: [qa | ckv] = hs @ [Wqa | Wkva] ---
  gemm_v3_kernel<1><<<dim3(17, 16), 256, 0, stream>>>(hs_bf, WabT, fused, 2048, 2112, 4096);

  // --- norms ---
  rmsnorm_kernel<<<2048, 256, 0, stream>>>(fused, qln, qan, 1536, 2112, 1536);
  rmsnorm_kernel<<<2048, 256, 0, stream>>>(fused + 1536, kvln, cn, 512, 2112, 512);

  // --- second-stage GEMMs ---
  gemm_v3_kernel<1><<<dim3(48, 16), 256, 0, stream>>>(qan, WqbT, q, 2048, 6144, 1536);
  gemm_v3_kernel<1><<<dim3(64, 16), 256, 0, stream>>>(cn, WkvbT, kv, 2048, 8192, 512);

  // --- head-major layouts + RoPE (vectorized) ---
  build_qf_kernel<<<6144, 256, 0, stream>>>(q, cost, sint, qfb);
  build_kf_kernel<<<6144, 256, 0, stream>>>(kv, fused + 1536, cost, sint, kfb);
  vt_build_kernel<<<dim3(32, 2, 32), 256, 0, stream>>>(kv, vTb);

  // --- attention (512 blocks, 2/CU, head-pinned XCD, paired) ---
  mla_attn_kernel<<<dim3(32, 16), 256, 0, stream>>>(qfb, kfb, vTb, ob);

  // --- output projection ---
  gemm_v3_kernel<0><<<dim3(32, 16), 256, 0, stream>>>(ob, WoT, out, 2048, 4096, 4096);
}